// Round 2
// baseline (4816.534 us; speedup 1.0000x reference)
//
#include <hip/hip_runtime.h>

#define ALPHA 0.005f
#define SCALE 0.001f
#define DELTA 0.1f
#define MAXIT 51   // MAX_ITER + 1 scan steps

constexpr int N = 512;
constexpr int M = 512;
constexpr int NTHREADS = 1024;
constexpr int NWAVES = NTHREADS / 64;  // 16
constexpr int MPW = M / NWAVES;        // 32 constraint rows per wave
constexpr int NROWS = 256;             // B*S
constexpr int UNROLL = 4;

// One block per (b,s) row, fully independent (per-row inactivity is absorbing,
// so the reference's global early-stop never changes the output — see journal).
// x lives in registers (replicated per wave); A is streamed once per iteration
// computing viol and g in one fused pass, software-pipelined 4 rows deep.
__global__ __launch_bounds__(NTHREADS, 4)
void lva_kernel(const float* __restrict__ x_in,
                const float* __restrict__ A,
                const float* __restrict__ bvec,
                float* __restrict__ x_out)
{
    __shared__ float b_lds[M];
    __shared__ float g_lds[NWAVES * N];   // 32 KiB partial-g
    __shared__ float sv_lds[NWAVES];
    __shared__ int bc_active;

    const int tid  = threadIdx.x;
    const int lane = tid & 63;
    const int w    = tid >> 6;
    const int r    = blockIdx.x;          // row index 0..255

    if (tid < M) b_lds[tid] = bvec[(size_t)r * M + tid];

    // lane's 8 n-indices: [4*lane .. 4*lane+3] and [256+4*lane .. 256+4*lane+3]
    const int n0 = lane * 4;
    const int n1 = 256 + lane * 4;

    const float* xrow = x_in + (size_t)r * N;
    float4 xa = *(const float4*)(xrow + n0);
    float4 xb = *(const float4*)(xrow + n1);

    // wave w handles constraint rows m = w + 16*k, k = 0..31
    const float* Ablk = A + (size_t)r * M * N + (size_t)w * N;

    __syncthreads();

    for (int t = 0; t < MAXIT; ++t) {
        float4 ga = make_float4(0.f, 0.f, 0.f, 0.f);
        float4 gb = make_float4(0.f, 0.f, 0.f, 0.f);
        float sviol = 0.f;

        float4 Aa[UNROLL], Ab[UNROLL];     // current group (4 rows x 32B/lane)
        #pragma unroll
        for (int j = 0; j < UNROLL; ++j) {
            const float* p = Ablk + (size_t)j * (16 * N);
            Aa[j] = *(const float4*)(p + n0);
            Ab[j] = *(const float4*)(p + n1);
        }

        #pragma unroll
        for (int kk = 0; kk < MPW; kk += UNROLL) {
            float4 Na[UNROLL], Nb[UNROLL]; // prefetch next group while computing
            if (kk + UNROLL < MPW) {
                #pragma unroll
                for (int j = 0; j < UNROLL; ++j) {
                    const float* p = Ablk + (size_t)(kk + UNROLL + j) * (16 * N);
                    Na[j] = *(const float4*)(p + n0);
                    Nb[j] = *(const float4*)(p + n1);
                }
            }
            float d[UNROLL];
            #pragma unroll
            for (int j = 0; j < UNROLL; ++j)
                d[j] = Aa[j].x*xa.x + Aa[j].y*xa.y + Aa[j].z*xa.z + Aa[j].w*xa.w
                     + Ab[j].x*xb.x + Ab[j].y*xb.y + Ab[j].z*xb.z + Ab[j].w*xb.w;
            // 4 independent butterfly chains interleave -> latency hidden
            #pragma unroll
            for (int off = 32; off > 0; off >>= 1) {
                #pragma unroll
                for (int j = 0; j < UNROLL; ++j)
                    d[j] += __shfl_xor(d[j], off, 64);
            }
            #pragma unroll
            for (int j = 0; j < UNROLL; ++j) {
                float v = d[j] - b_lds[w + 16 * (kk + j)];
                v = v > 0.f ? v : 0.f;
                sviol += v;
                ga.x += v*Aa[j].x; ga.y += v*Aa[j].y; ga.z += v*Aa[j].z; ga.w += v*Aa[j].w;
                gb.x += v*Ab[j].x; gb.y += v*Ab[j].y; gb.z += v*Ab[j].z; gb.w += v*Ab[j].w;
            }
            #pragma unroll
            for (int j = 0; j < UNROLL; ++j) { Aa[j] = Na[j]; Ab[j] = Nb[j]; }
        }

        if (lane == 0) sv_lds[w] = sviol;
        *(float4*)(&g_lds[w * N + n0]) = ga;
        *(float4*)(&g_lds[w * N + n1]) = gb;
        __syncthreads();
        if (tid == 0) {
            float s = 0.f;
            #pragma unroll
            for (int i = 0; i < NWAVES; ++i) s += sv_lds[i];
            bc_active = (s >= DELTA) ? 1 : 0;
        }
        if (tid < N) {                     // cross-wave g reduce (column tid)
            float s = 0.f;
            #pragma unroll
            for (int i = 0; i < NWAVES; ++i) s += g_lds[i * N + tid];
            g_lds[tid] = s;
        }
        __syncthreads();
        if (!bc_active) break;             // row deactivated: x frozen forever

        float4 gfa = *(const float4*)(&g_lds[n0]);
        float4 gfb = *(const float4*)(&g_lds[n1]);
        xa.x = fmaxf(xa.x - (ALPHA / (1.f + SCALE*gfa.x)) * gfa.x, 0.f);
        xa.y = fmaxf(xa.y - (ALPHA / (1.f + SCALE*gfa.y)) * gfa.y, 0.f);
        xa.z = fmaxf(xa.z - (ALPHA / (1.f + SCALE*gfa.z)) * gfa.z, 0.f);
        xa.w = fmaxf(xa.w - (ALPHA / (1.f + SCALE*gfa.w)) * gfa.w, 0.f);
        xb.x = fmaxf(xb.x - (ALPHA / (1.f + SCALE*gfb.x)) * gfb.x, 0.f);
        xb.y = fmaxf(xb.y - (ALPHA / (1.f + SCALE*gfb.y)) * gfb.y, 0.f);
        xb.z = fmaxf(xb.z - (ALPHA / (1.f + SCALE*gfb.z)) * gfb.z, 0.f);
        xb.w = fmaxf(xb.w - (ALPHA / (1.f + SCALE*gfb.w)) * gfb.w, 0.f);
        __syncthreads();                   // protect g_lds before next iter's writes
    }

    float* orow = x_out + (size_t)r * N;
    if (w == 0) {   // x replicated & identical across waves; wave 0 writes
        *(float4*)(orow + n0) = xa;
        *(float4*)(orow + n1) = xb;
    }
}

extern "C" void kernel_launch(void* const* d_in, const int* in_sizes, int n_in,
                              void* d_out, int out_size, void* d_ws, size_t ws_size,
                              hipStream_t stream)
{
    const float* x  = (const float*)d_in[0];
    const float* A  = (const float*)d_in[1];
    const float* b  = (const float*)d_in[2];
    float* out      = (float*)d_out;

    lva_kernel<<<dim3(NROWS), dim3(NTHREADS), 0, stream>>>(x, A, b, out);
}

// Round 3
// 2235.601 us; speedup vs baseline: 2.1545x; 2.1545x over previous
//
#include <hip/hip_runtime.h>

#define ALPHA 0.005f
#define SCALE 0.001f
#define DELTA 0.1f
#define MAXIT 51   // MAX_ITER + 1 scan steps

constexpr int N = 512;
constexpr int M = 512;
constexpr int NTHREADS = 1024;
constexpr int NWAVES = NTHREADS / 64;  // 16
constexpr int MPW = M / NWAVES;        // 32 constraint rows per wave
constexpr int NROWS = 256;             // B*S

// Cross-lane wave64 sum on the VALU pipe (DPP), not the LDS pipe.
// row_shr:1/2/4/8 -> per-16-lane-row sums in lanes 15/31/47/63;
// row_bcast:15 -> lane31 = sum(0..31); row_bcast:31 -> lane63 = total.
template<int CTRL>
__device__ __forceinline__ float dpp_mov(float v) {
    return __int_as_float(__builtin_amdgcn_update_dpp(
        0, __float_as_int(v), CTRL, 0xF, 0xF, true));
}

__device__ __forceinline__ float wave_sum_u(float d) {
    d += dpp_mov<0x111>(d);   // row_shr:1
    d += dpp_mov<0x112>(d);   // row_shr:2
    d += dpp_mov<0x114>(d);   // row_shr:4
    d += dpp_mov<0x118>(d);   // row_shr:8
    d += dpp_mov<0x142>(d);   // row_bcast:15
    d += dpp_mov<0x143>(d);   // row_bcast:31
    // lane 63 holds the full sum; broadcast via SGPR (uniform)
    return __int_as_float(__builtin_amdgcn_readlane(__float_as_int(d), 63));
}

__device__ __forceinline__ float dot8(const float4& a, const float4& c,
                                      const float4& xa, const float4& xb) {
    return a.x*xa.x + a.y*xa.y + a.z*xa.z + a.w*xa.w
         + c.x*xb.x + c.y*xb.y + c.z*xb.z + c.w*xb.w;
}

// One block per (b,s) row, fully independent (per-row inactivity is absorbing;
// validated vs reference in rounds 1-2). x lives in registers; A streamed once
// per iteration, 4 constraint rows per step (8 KB/wave in flight), fused
// viol + g accumulation, DPP dot-reduction (no LDS-pipe latency chain).
__global__ __launch_bounds__(NTHREADS, 4)
void lva_kernel(const float* __restrict__ x_in,
                const float* __restrict__ A,
                const float* __restrict__ bvec,
                float* __restrict__ x_out)
{
    __shared__ float b_lds[M];
    __shared__ float g_lds[NWAVES * N];   // 32 KiB partial-g
    __shared__ float sv_lds[NWAVES];
    __shared__ int bc_active;

    const int tid  = threadIdx.x;
    const int lane = tid & 63;
    const int w    = tid >> 6;
    const int r    = blockIdx.x;          // row index 0..255

    if (tid < M) b_lds[tid] = bvec[(size_t)r * M + tid];

    const int n0 = lane * 4;
    const int n1 = 256 + lane * 4;

    const float* xrow = x_in + (size_t)r * N;
    float4 xa = *(const float4*)(xrow + n0);
    float4 xb = *(const float4*)(xrow + n1);

    // wave w handles constraint rows m = w + 16*k, k = 0..31
    const float* Ablk = A + (size_t)r * M * N + (size_t)w * N;

    __syncthreads();

    for (int t = 0; t < MAXIT; ++t) {
        float4 ga = make_float4(0.f, 0.f, 0.f, 0.f);
        float4 gb = make_float4(0.f, 0.f, 0.f, 0.f);
        float sviol = 0.f;   // wave-uniform by construction (viol from SGPR)

        #pragma unroll 1
        for (int kk = 0; kk < MPW; kk += 4) {
            const float* p0 = Ablk + (size_t)(kk + 0) * (16 * N);
            const float* p1 = Ablk + (size_t)(kk + 1) * (16 * N);
            const float* p2 = Ablk + (size_t)(kk + 2) * (16 * N);
            const float* p3 = Ablk + (size_t)(kk + 3) * (16 * N);
            // 8 independent 16B loads issue together: 8 KB/wave in flight
            float4 a0 = *(const float4*)(p0 + n0), c0 = *(const float4*)(p0 + n1);
            float4 a1 = *(const float4*)(p1 + n0), c1 = *(const float4*)(p1 + n1);
            float4 a2 = *(const float4*)(p2 + n0), c2 = *(const float4*)(p2 + n1);
            float4 a3 = *(const float4*)(p3 + n0), c3 = *(const float4*)(p3 + n1);
            float bb0 = b_lds[w + 16 * (kk + 0)];
            float bb1 = b_lds[w + 16 * (kk + 1)];
            float bb2 = b_lds[w + 16 * (kk + 2)];
            float bb3 = b_lds[w + 16 * (kk + 3)];
            // 4 independent DPP reduction chains interleave
            float d0 = wave_sum_u(dot8(a0, c0, xa, xb));
            float d1 = wave_sum_u(dot8(a1, c1, xa, xb));
            float d2 = wave_sum_u(dot8(a2, c2, xa, xb));
            float d3 = wave_sum_u(dot8(a3, c3, xa, xb));
            float v0 = fmaxf(d0 - bb0, 0.f);
            float v1 = fmaxf(d1 - bb1, 0.f);
            float v2 = fmaxf(d2 - bb2, 0.f);
            float v3 = fmaxf(d3 - bb3, 0.f);
            sviol += v0 + v1 + v2 + v3;
            // g += viol * A[m,:], reusing A registers
            ga.x += v0*a0.x + v1*a1.x + v2*a2.x + v3*a3.x;
            ga.y += v0*a0.y + v1*a1.y + v2*a2.y + v3*a3.y;
            ga.z += v0*a0.z + v1*a1.z + v2*a2.z + v3*a3.z;
            ga.w += v0*a0.w + v1*a1.w + v2*a2.w + v3*a3.w;
            gb.x += v0*c0.x + v1*c1.x + v2*c2.x + v3*c3.x;
            gb.y += v0*c0.y + v1*c1.y + v2*c2.y + v3*c3.y;
            gb.z += v0*c0.z + v1*c1.z + v2*c2.z + v3*c3.z;
            gb.w += v0*c0.w + v1*c1.w + v2*c2.w + v3*c3.w;
        }

        if (lane == 0) sv_lds[w] = sviol;
        *(float4*)(&g_lds[w * N + n0]) = ga;
        *(float4*)(&g_lds[w * N + n1]) = gb;
        __syncthreads();
        if (tid == 0) {
            float s = 0.f;
            #pragma unroll
            for (int i = 0; i < NWAVES; ++i) s += sv_lds[i];
            bc_active = (s >= DELTA) ? 1 : 0;
        }
        if (tid < N) {                     // cross-wave g reduce (column tid)
            float s = 0.f;
            #pragma unroll
            for (int i = 0; i < NWAVES; ++i) s += g_lds[i * N + tid];
            g_lds[tid] = s;
        }
        __syncthreads();
        if (!bc_active) break;             // row deactivated: x frozen forever

        float4 gfa = *(const float4*)(&g_lds[n0]);
        float4 gfb = *(const float4*)(&g_lds[n1]);
        xa.x = fmaxf(xa.x - (ALPHA / (1.f + SCALE*gfa.x)) * gfa.x, 0.f);
        xa.y = fmaxf(xa.y - (ALPHA / (1.f + SCALE*gfa.y)) * gfa.y, 0.f);
        xa.z = fmaxf(xa.z - (ALPHA / (1.f + SCALE*gfa.z)) * gfa.z, 0.f);
        xa.w = fmaxf(xa.w - (ALPHA / (1.f + SCALE*gfa.w)) * gfa.w, 0.f);
        xb.x = fmaxf(xb.x - (ALPHA / (1.f + SCALE*gfb.x)) * gfb.x, 0.f);
        xb.y = fmaxf(xb.y - (ALPHA / (1.f + SCALE*gfb.y)) * gfb.y, 0.f);
        xb.z = fmaxf(xb.z - (ALPHA / (1.f + SCALE*gfb.z)) * gfb.z, 0.f);
        xb.w = fmaxf(xb.w - (ALPHA / (1.f + SCALE*gfb.w)) * gfb.w, 0.f);
        __syncthreads();                   // protect g_lds before next iter's writes
    }

    float* orow = x_out + (size_t)r * N;
    if (w == 0) {   // x replicated & identical across waves; wave 0 writes
        *(float4*)(orow + n0) = xa;
        *(float4*)(orow + n1) = xb;
    }
}

extern "C" void kernel_launch(void* const* d_in, const int* in_sizes, int n_in,
                              void* d_out, int out_size, void* d_ws, size_t ws_size,
                              hipStream_t stream)
{
    const float* x  = (const float*)d_in[0];
    const float* A  = (const float*)d_in[1];
    const float* b  = (const float*)d_in[2];
    float* out      = (float*)d_out;

    lva_kernel<<<dim3(NROWS), dim3(NTHREADS), 0, stream>>>(x, A, b, out);
}

// Round 4
// 1299.788 us; speedup vs baseline: 3.7056x; 1.7200x over previous
//
#include <hip/hip_runtime.h>

#define ALPHA 0.005f
#define SCALE 0.001f
#define DELTA 0.1f
#define MAXIT 51   // MAX_ITER + 1 scan steps

constexpr int N = 512;
constexpr int M = 512;
constexpr int NTHREADS = 1024;
constexpr int NWAVES = NTHREADS / 64;  // 16
constexpr int MPW = M / NWAVES;        // 32 constraint rows per wave
constexpr int NROWS = 256;             // B*S
constexpr size_t WS_NEEDED = (size_t)NROWS * M * N * 2;  // bf16 A copy: 128 MiB

// Cross-lane wave64 sum on the VALU pipe (DPP), not the LDS pipe.
template<int CTRL>
__device__ __forceinline__ float dpp_mov(float v) {
    return __int_as_float(__builtin_amdgcn_update_dpp(
        0, __float_as_int(v), CTRL, 0xF, 0xF, true));
}

__device__ __forceinline__ float wave_sum_u(float d) {
    d += dpp_mov<0x111>(d);   // row_shr:1
    d += dpp_mov<0x112>(d);   // row_shr:2
    d += dpp_mov<0x114>(d);   // row_shr:4
    d += dpp_mov<0x118>(d);   // row_shr:8
    d += dpp_mov<0x142>(d);   // row_bcast:15
    d += dpp_mov<0x143>(d);   // row_bcast:31
    return __int_as_float(__builtin_amdgcn_readlane(__float_as_int(d), 63));
}

__device__ __forceinline__ float dot8(const float4& a, const float4& c,
                                      const float4& xa, const float4& xb) {
    return a.x*xa.x + a.y*xa.y + a.z*xa.z + a.w*xa.w
         + c.x*xb.x + c.y*xb.y + c.z*xb.z + c.w*xb.w;
}

// bf16 pack (RNE) / unpack helpers
__device__ __forceinline__ unsigned pack2_bf16(float f0, float f1) {
    unsigned a = __float_as_uint(f0); a += 0x7fffu + ((a >> 16) & 1u);
    unsigned b = __float_as_uint(f1); b += 0x7fffu + ((b >> 16) & 1u);
    return (a >> 16) | (b & 0xffff0000u);
}
__device__ __forceinline__ float bflo(unsigned u) { return __uint_as_float(u << 16); }
__device__ __forceinline__ float bfhi(unsigned u) { return __uint_as_float(u & 0xffff0000u); }

// ---------------------------------------------------------------------------
// Main kernel: one block per (b,s) row, fully independent (per-row inactivity
// is absorbing — validated rounds 1-3). t=0 streams fp32 A, computing the
// first update AND storing a bf16 copy of A into workspace. t>=1 iterate on
// the bf16 copy: half the traffic, and the 128 MiB working set is
// Infinity-Cache resident.
// ---------------------------------------------------------------------------
__global__ __launch_bounds__(NTHREADS, 4)
void lva_bf16_kernel(const float* __restrict__ x_in,
                     const float* __restrict__ A,
                     const float* __restrict__ bvec,
                     float* __restrict__ x_out,
                     unsigned short* __restrict__ wsA)
{
    __shared__ float b_lds[M];
    __shared__ float g_lds[NWAVES * N];   // 32 KiB partial-g
    __shared__ float sv_lds[NWAVES];
    __shared__ int bc_active;

    const int tid  = threadIdx.x;
    const int lane = tid & 63;
    const int w    = tid >> 6;
    const int r    = blockIdx.x;

    if (tid < M) b_lds[tid] = bvec[(size_t)r * M + tid];

    const int n0 = lane * 4;
    const int n1 = 256 + lane * 4;

    const float* xrow = x_in + (size_t)r * N;
    float4 xa = *(const float4*)(xrow + n0);
    float4 xb = *(const float4*)(xrow + n1);

    // wave w handles constraint rows m = w + 16*k, k = 0..31
    const float* Ablk = A + (size_t)r * M * N + (size_t)w * N;
    unsigned short* Wblk = wsA + (size_t)r * M * N + (size_t)w * N;

    __syncthreads();

    bool alive = true;

    // ---- t = 0: fp32 compute + bf16 convert/store (fused) ----
    {
        float4 ga = make_float4(0.f, 0.f, 0.f, 0.f);
        float4 gb = make_float4(0.f, 0.f, 0.f, 0.f);
        float sviol = 0.f;

        #pragma unroll 1
        for (int kk = 0; kk < MPW; kk += 4) {
            const float* p0 = Ablk + (size_t)(kk + 0) * (16 * N);
            const float* p1 = Ablk + (size_t)(kk + 1) * (16 * N);
            const float* p2 = Ablk + (size_t)(kk + 2) * (16 * N);
            const float* p3 = Ablk + (size_t)(kk + 3) * (16 * N);
            float4 a0 = *(const float4*)(p0 + n0), c0 = *(const float4*)(p0 + n1);
            float4 a1 = *(const float4*)(p1 + n0), c1 = *(const float4*)(p1 + n1);
            float4 a2 = *(const float4*)(p2 + n0), c2 = *(const float4*)(p2 + n1);
            float4 a3 = *(const float4*)(p3 + n0), c3 = *(const float4*)(p3 + n1);
            // store bf16 copy (one-time, coalesced 512B/inst)
            {
                unsigned short* q0 = Wblk + (size_t)(kk + 0) * (16 * N);
                unsigned short* q1 = Wblk + (size_t)(kk + 1) * (16 * N);
                unsigned short* q2 = Wblk + (size_t)(kk + 2) * (16 * N);
                unsigned short* q3 = Wblk + (size_t)(kk + 3) * (16 * N);
                *(uint2*)(q0 + n0) = make_uint2(pack2_bf16(a0.x, a0.y), pack2_bf16(a0.z, a0.w));
                *(uint2*)(q0 + n1) = make_uint2(pack2_bf16(c0.x, c0.y), pack2_bf16(c0.z, c0.w));
                *(uint2*)(q1 + n0) = make_uint2(pack2_bf16(a1.x, a1.y), pack2_bf16(a1.z, a1.w));
                *(uint2*)(q1 + n1) = make_uint2(pack2_bf16(c1.x, c1.y), pack2_bf16(c1.z, c1.w));
                *(uint2*)(q2 + n0) = make_uint2(pack2_bf16(a2.x, a2.y), pack2_bf16(a2.z, a2.w));
                *(uint2*)(q2 + n1) = make_uint2(pack2_bf16(c2.x, c2.y), pack2_bf16(c2.z, c2.w));
                *(uint2*)(q3 + n0) = make_uint2(pack2_bf16(a3.x, a3.y), pack2_bf16(a3.z, a3.w));
                *(uint2*)(q3 + n1) = make_uint2(pack2_bf16(c3.x, c3.y), pack2_bf16(c3.z, c3.w));
            }
            float bb0 = b_lds[w + 16 * (kk + 0)];
            float bb1 = b_lds[w + 16 * (kk + 1)];
            float bb2 = b_lds[w + 16 * (kk + 2)];
            float bb3 = b_lds[w + 16 * (kk + 3)];
            float d0 = wave_sum_u(dot8(a0, c0, xa, xb));
            float d1 = wave_sum_u(dot8(a1, c1, xa, xb));
            float d2 = wave_sum_u(dot8(a2, c2, xa, xb));
            float d3 = wave_sum_u(dot8(a3, c3, xa, xb));
            float v0 = fmaxf(d0 - bb0, 0.f);
            float v1 = fmaxf(d1 - bb1, 0.f);
            float v2 = fmaxf(d2 - bb2, 0.f);
            float v3 = fmaxf(d3 - bb3, 0.f);
            sviol += v0 + v1 + v2 + v3;
            ga.x += v0*a0.x + v1*a1.x + v2*a2.x + v3*a3.x;
            ga.y += v0*a0.y + v1*a1.y + v2*a2.y + v3*a3.y;
            ga.z += v0*a0.z + v1*a1.z + v2*a2.z + v3*a3.z;
            ga.w += v0*a0.w + v1*a1.w + v2*a2.w + v3*a3.w;
            gb.x += v0*c0.x + v1*c1.x + v2*c2.x + v3*c3.x;
            gb.y += v0*c0.y + v1*c1.y + v2*c2.y + v3*c3.y;
            gb.z += v0*c0.z + v1*c1.z + v2*c2.z + v3*c3.z;
            gb.w += v0*c0.w + v1*c1.w + v2*c2.w + v3*c3.w;
        }

        if (lane == 0) sv_lds[w] = sviol;
        *(float4*)(&g_lds[w * N + n0]) = ga;
        *(float4*)(&g_lds[w * N + n1]) = gb;
        __syncthreads();
        if (tid == 0) {
            float s = 0.f;
            #pragma unroll
            for (int i = 0; i < NWAVES; ++i) s += sv_lds[i];
            bc_active = (s >= DELTA) ? 1 : 0;
        }
        if (tid < N) {
            float s = 0.f;
            #pragma unroll
            for (int i = 0; i < NWAVES; ++i) s += g_lds[i * N + tid];
            g_lds[tid] = s;
        }
        __syncthreads();
        if (!bc_active) {
            alive = false;
        } else {
            float4 gfa = *(const float4*)(&g_lds[n0]);
            float4 gfb = *(const float4*)(&g_lds[n1]);
            xa.x = fmaxf(xa.x - (ALPHA / (1.f + SCALE*gfa.x)) * gfa.x, 0.f);
            xa.y = fmaxf(xa.y - (ALPHA / (1.f + SCALE*gfa.y)) * gfa.y, 0.f);
            xa.z = fmaxf(xa.z - (ALPHA / (1.f + SCALE*gfa.z)) * gfa.z, 0.f);
            xa.w = fmaxf(xa.w - (ALPHA / (1.f + SCALE*gfa.w)) * gfa.w, 0.f);
            xb.x = fmaxf(xb.x - (ALPHA / (1.f + SCALE*gfb.x)) * gfb.x, 0.f);
            xb.y = fmaxf(xb.y - (ALPHA / (1.f + SCALE*gfb.y)) * gfb.y, 0.f);
            xb.z = fmaxf(xb.z - (ALPHA / (1.f + SCALE*gfb.z)) * gfb.z, 0.f);
            xb.w = fmaxf(xb.w - (ALPHA / (1.f + SCALE*gfb.w)) * gfb.w, 0.f);
            __syncthreads();
        }
    }

    // ---- t = 1..50: iterate on the L3-resident bf16 copy ----
    if (alive) {
        for (int t = 1; t < MAXIT; ++t) {
            float4 ga = make_float4(0.f, 0.f, 0.f, 0.f);
            float4 gb = make_float4(0.f, 0.f, 0.f, 0.f);
            float sviol = 0.f;

            #pragma unroll 1
            for (int kk = 0; kk < MPW; kk += 8) {
                uint2 qa[8], qb[8];
                #pragma unroll
                for (int j = 0; j < 8; ++j) {
                    const unsigned short* p = Wblk + (size_t)(kk + j) * (16 * N);
                    qa[j] = *(const uint2*)(p + n0);   // 8B/lane, 512B/inst coalesced
                    qb[j] = *(const uint2*)(p + n1);
                }
                float d[8];
                #pragma unroll
                for (int j = 0; j < 8; ++j)
                    d[j] = bflo(qa[j].x)*xa.x + bfhi(qa[j].x)*xa.y
                         + bflo(qa[j].y)*xa.z + bfhi(qa[j].y)*xa.w
                         + bflo(qb[j].x)*xb.x + bfhi(qb[j].x)*xb.y
                         + bflo(qb[j].y)*xb.z + bfhi(qb[j].y)*xb.w;
                #pragma unroll
                for (int j = 0; j < 8; ++j) d[j] = wave_sum_u(d[j]);
                #pragma unroll
                for (int j = 0; j < 8; ++j) {
                    float v = fmaxf(d[j] - b_lds[w + 16 * (kk + j)], 0.f);
                    sviol += v;
                    ga.x += v*bflo(qa[j].x); ga.y += v*bfhi(qa[j].x);
                    ga.z += v*bflo(qa[j].y); ga.w += v*bfhi(qa[j].y);
                    gb.x += v*bflo(qb[j].x); gb.y += v*bfhi(qb[j].x);
                    gb.z += v*bflo(qb[j].y); gb.w += v*bfhi(qb[j].y);
                }
            }

            if (lane == 0) sv_lds[w] = sviol;
            *(float4*)(&g_lds[w * N + n0]) = ga;
            *(float4*)(&g_lds[w * N + n1]) = gb;
            __syncthreads();
            if (tid == 0) {
                float s = 0.f;
                #pragma unroll
                for (int i = 0; i < NWAVES; ++i) s += sv_lds[i];
                bc_active = (s >= DELTA) ? 1 : 0;
            }
            if (tid < N) {
                float s = 0.f;
                #pragma unroll
                for (int i = 0; i < NWAVES; ++i) s += g_lds[i * N + tid];
                g_lds[tid] = s;
            }
            __syncthreads();
            if (!bc_active) break;

            float4 gfa = *(const float4*)(&g_lds[n0]);
            float4 gfb = *(const float4*)(&g_lds[n1]);
            xa.x = fmaxf(xa.x - (ALPHA / (1.f + SCALE*gfa.x)) * gfa.x, 0.f);
            xa.y = fmaxf(xa.y - (ALPHA / (1.f + SCALE*gfa.y)) * gfa.y, 0.f);
            xa.z = fmaxf(xa.z - (ALPHA / (1.f + SCALE*gfa.z)) * gfa.z, 0.f);
            xa.w = fmaxf(xa.w - (ALPHA / (1.f + SCALE*gfa.w)) * gfa.w, 0.f);
            xb.x = fmaxf(xb.x - (ALPHA / (1.f + SCALE*gfb.x)) * gfb.x, 0.f);
            xb.y = fmaxf(xb.y - (ALPHA / (1.f + SCALE*gfb.y)) * gfb.y, 0.f);
            xb.z = fmaxf(xb.z - (ALPHA / (1.f + SCALE*gfb.z)) * gfb.z, 0.f);
            xb.w = fmaxf(xb.w - (ALPHA / (1.f + SCALE*gfb.w)) * gfb.w, 0.f);
            __syncthreads();
        }
    }

    float* orow = x_out + (size_t)r * N;
    if (w == 0) {
        *(float4*)(orow + n0) = xa;
        *(float4*)(orow + n1) = xb;
    }
}

// ---------------------------------------------------------------------------
// Fallback (round-3 proven kernel, fp32 all the way) if ws_size < 128 MiB.
// ---------------------------------------------------------------------------
__global__ __launch_bounds__(NTHREADS, 4)
void lva_kernel(const float* __restrict__ x_in,
                const float* __restrict__ A,
                const float* __restrict__ bvec,
                float* __restrict__ x_out)
{
    __shared__ float b_lds[M];
    __shared__ float g_lds[NWAVES * N];
    __shared__ float sv_lds[NWAVES];
    __shared__ int bc_active;

    const int tid  = threadIdx.x;
    const int lane = tid & 63;
    const int w    = tid >> 6;
    const int r    = blockIdx.x;

    if (tid < M) b_lds[tid] = bvec[(size_t)r * M + tid];

    const int n0 = lane * 4;
    const int n1 = 256 + lane * 4;

    const float* xrow = x_in + (size_t)r * N;
    float4 xa = *(const float4*)(xrow + n0);
    float4 xb = *(const float4*)(xrow + n1);

    const float* Ablk = A + (size_t)r * M * N + (size_t)w * N;

    __syncthreads();

    for (int t = 0; t < MAXIT; ++t) {
        float4 ga = make_float4(0.f, 0.f, 0.f, 0.f);
        float4 gb = make_float4(0.f, 0.f, 0.f, 0.f);
        float sviol = 0.f;

        #pragma unroll 1
        for (int kk = 0; kk < MPW; kk += 4) {
            const float* p0 = Ablk + (size_t)(kk + 0) * (16 * N);
            const float* p1 = Ablk + (size_t)(kk + 1) * (16 * N);
            const float* p2 = Ablk + (size_t)(kk + 2) * (16 * N);
            const float* p3 = Ablk + (size_t)(kk + 3) * (16 * N);
            float4 a0 = *(const float4*)(p0 + n0), c0 = *(const float4*)(p0 + n1);
            float4 a1 = *(const float4*)(p1 + n0), c1 = *(const float4*)(p1 + n1);
            float4 a2 = *(const float4*)(p2 + n0), c2 = *(const float4*)(p2 + n1);
            float4 a3 = *(const float4*)(p3 + n0), c3 = *(const float4*)(p3 + n1);
            float bb0 = b_lds[w + 16 * (kk + 0)];
            float bb1 = b_lds[w + 16 * (kk + 1)];
            float bb2 = b_lds[w + 16 * (kk + 2)];
            float bb3 = b_lds[w + 16 * (kk + 3)];
            float d0 = wave_sum_u(dot8(a0, c0, xa, xb));
            float d1 = wave_sum_u(dot8(a1, c1, xa, xb));
            float d2 = wave_sum_u(dot8(a2, c2, xa, xb));
            float d3 = wave_sum_u(dot8(a3, c3, xa, xb));
            float v0 = fmaxf(d0 - bb0, 0.f);
            float v1 = fmaxf(d1 - bb1, 0.f);
            float v2 = fmaxf(d2 - bb2, 0.f);
            float v3 = fmaxf(d3 - bb3, 0.f);
            sviol += v0 + v1 + v2 + v3;
            ga.x += v0*a0.x + v1*a1.x + v2*a2.x + v3*a3.x;
            ga.y += v0*a0.y + v1*a1.y + v2*a2.y + v3*a3.y;
            ga.z += v0*a0.z + v1*a1.z + v2*a2.z + v3*a3.z;
            ga.w += v0*a0.w + v1*a1.w + v2*a2.w + v3*a3.w;
            gb.x += v0*c0.x + v1*c1.x + v2*c2.x + v3*c3.x;
            gb.y += v0*c0.y + v1*c1.y + v2*c2.y + v3*c3.y;
            gb.z += v0*c0.z + v1*c1.z + v2*c2.z + v3*c3.z;
            gb.w += v0*c0.w + v1*c1.w + v2*c2.w + v3*c3.w;
        }

        if (lane == 0) sv_lds[w] = sviol;
        *(float4*)(&g_lds[w * N + n0]) = ga;
        *(float4*)(&g_lds[w * N + n1]) = gb;
        __syncthreads();
        if (tid == 0) {
            float s = 0.f;
            #pragma unroll
            for (int i = 0; i < NWAVES; ++i) s += sv_lds[i];
            bc_active = (s >= DELTA) ? 1 : 0;
        }
        if (tid < N) {
            float s = 0.f;
            #pragma unroll
            for (int i = 0; i < NWAVES; ++i) s += g_lds[i * N + tid];
            g_lds[tid] = s;
        }
        __syncthreads();
        if (!bc_active) break;

        float4 gfa = *(const float4*)(&g_lds[n0]);
        float4 gfb = *(const float4*)(&g_lds[n1]);
        xa.x = fmaxf(xa.x - (ALPHA / (1.f + SCALE*gfa.x)) * gfa.x, 0.f);
        xa.y = fmaxf(xa.y - (ALPHA / (1.f + SCALE*gfa.y)) * gfa.y, 0.f);
        xa.z = fmaxf(xa.z - (ALPHA / (1.f + SCALE*gfa.z)) * gfa.z, 0.f);
        xa.w = fmaxf(xa.w - (ALPHA / (1.f + SCALE*gfa.w)) * gfa.w, 0.f);
        xb.x = fmaxf(xb.x - (ALPHA / (1.f + SCALE*gfb.x)) * gfb.x, 0.f);
        xb.y = fmaxf(xb.y - (ALPHA / (1.f + SCALE*gfb.y)) * gfb.y, 0.f);
        xb.z = fmaxf(xb.z - (ALPHA / (1.f + SCALE*gfb.z)) * gfb.z, 0.f);
        xb.w = fmaxf(xb.w - (ALPHA / (1.f + SCALE*gfb.w)) * gfb.w, 0.f);
        __syncthreads();
    }

    float* orow = x_out + (size_t)r * N;
    if (w == 0) {
        *(float4*)(orow + n0) = xa;
        *(float4*)(orow + n1) = xb;
    }
}

extern "C" void kernel_launch(void* const* d_in, const int* in_sizes, int n_in,
                              void* d_out, int out_size, void* d_ws, size_t ws_size,
                              hipStream_t stream)
{
    const float* x  = (const float*)d_in[0];
    const float* A  = (const float*)d_in[1];
    const float* b  = (const float*)d_in[2];
    float* out      = (float*)d_out;

    if (ws_size >= WS_NEEDED) {
        lva_bf16_kernel<<<dim3(NROWS), dim3(NTHREADS), 0, stream>>>(
            x, A, b, out, (unsigned short*)d_ws);
    } else {
        lva_kernel<<<dim3(NROWS), dim3(NTHREADS), 0, stream>>>(x, A, b, out);
    }
}

// Round 5
// 1285.477 us; speedup vs baseline: 3.7469x; 1.0111x over previous
//
#include <hip/hip_runtime.h>

#define ALPHA 0.005f
#define SCALE 0.001f
#define DELTA 0.1f
#define MAXIT 51   // MAX_ITER + 1 scan steps

constexpr int N = 512;
constexpr int M = 512;
constexpr int NTHREADS = 1024;
constexpr int NWAVES = NTHREADS / 64;  // 16
constexpr int MPW = M / NWAVES;        // 32 constraint rows per wave
constexpr int NROWS = 256;             // B*S
constexpr size_t WS_NEEDED = (size_t)NROWS * M * N * 2;  // bf16 A copy: 128 MiB

template<int CTRL>
__device__ __forceinline__ float dpp_mov(float v) {
    return __int_as_float(__builtin_amdgcn_update_dpp(
        0, __float_as_int(v), CTRL, 0xF, 0xF, true));
}

// 64-lane sum (used in t=0 fp32 phase): 6 DPP + readlane
__device__ __forceinline__ float wave_sum_u(float d) {
    d += dpp_mov<0x111>(d);   // row_shr:1
    d += dpp_mov<0x112>(d);   // row_shr:2
    d += dpp_mov<0x114>(d);   // row_shr:4
    d += dpp_mov<0x118>(d);   // row_shr:8
    d += dpp_mov<0x142>(d);   // row_bcast:15
    d += dpp_mov<0x143>(d);   // row_bcast:31
    return __int_as_float(__builtin_amdgcn_readlane(__float_as_int(d), 63));
}

__device__ __forceinline__ float dot8(const float4& a, const float4& c,
                                      const float4& xa, const float4& xb) {
    return a.x*xa.x + a.y*xa.y + a.z*xa.z + a.w*xa.w
         + c.x*xb.x + c.y*xb.y + c.z*xb.z + c.w*xb.w;
}

// bf16 pack (RNE) / unpack
__device__ __forceinline__ unsigned pack2_bf16(float f0, float f1) {
    unsigned a = __float_as_uint(f0); a += 0x7fffu + ((a >> 16) & 1u);
    unsigned b = __float_as_uint(f1); b += 0x7fffu + ((b >> 16) & 1u);
    return (a >> 16) | (b & 0xffff0000u);
}
__device__ __forceinline__ float bflo(unsigned u) { return __uint_as_float(u << 16); }
__device__ __forceinline__ float bfhi(unsigned u) { return __uint_as_float(u & 0xffff0000u); }

__device__ __forceinline__ void unpack4(uint2 u, float4& f) {
    f.x = bflo(u.x); f.y = bfhi(u.x); f.z = bflo(u.y); f.w = bfhi(u.y);
}

// ---------------------------------------------------------------------------
// One block per (b,s) row (per-row inactivity is absorbing — validated r1-r4).
// t=0: fp32 pass (64-lane layout) computes update #1 and stores bf16 A to ws.
// t>=1: 32-lane-group layout — each half-wave owns one constraint row
// (16 elems/lane), double-buffered loads (always in flight), 16-lane DPP
// butterfly + ds_swizzle xor16 reduction (5 ops vs 13), per-half g partials
// reduced through 64 KiB LDS.
// ---------------------------------------------------------------------------
__global__ __launch_bounds__(NTHREADS, 4)
void lva_bf16_kernel(const float* __restrict__ x_in,
                     const float* __restrict__ A,
                     const float* __restrict__ bvec,
                     float* __restrict__ x_out,
                     unsigned short* __restrict__ wsA)
{
    __shared__ float b_lds[M];
    __shared__ float g_lds[2 * NWAVES * N];   // 64 KiB: 32 half-wave rows x 512
    __shared__ float sv_lds[2 * NWAVES];
    __shared__ int bc_active;

    const int tid  = threadIdx.x;
    const int lane = tid & 63;
    const int w    = tid >> 6;
    const int r    = blockIdx.x;

    if (tid < M) b_lds[tid] = bvec[(size_t)r * M + tid];

    const int n0 = lane * 4;
    const int n1 = 256 + lane * 4;

    const float* xrow = x_in + (size_t)r * N;
    float4 xa = *(const float4*)(xrow + n0);
    float4 xb = *(const float4*)(xrow + n1);

    const float* Ablk = A + (size_t)r * M * N + (size_t)w * N;
    unsigned short* Wblk = wsA + (size_t)r * M * N + (size_t)w * N;

    __syncthreads();

    bool alive = true;

    // ---- t = 0: fp32 compute + bf16 convert/store (proven r4 structure) ----
    {
        float4 ga = make_float4(0.f, 0.f, 0.f, 0.f);
        float4 gb = make_float4(0.f, 0.f, 0.f, 0.f);
        float sviol = 0.f;

        #pragma unroll 1
        for (int kk = 0; kk < MPW; kk += 4) {
            const float* p0 = Ablk + (size_t)(kk + 0) * (16 * N);
            const float* p1 = Ablk + (size_t)(kk + 1) * (16 * N);
            const float* p2 = Ablk + (size_t)(kk + 2) * (16 * N);
            const float* p3 = Ablk + (size_t)(kk + 3) * (16 * N);
            float4 a0 = *(const float4*)(p0 + n0), c0 = *(const float4*)(p0 + n1);
            float4 a1 = *(const float4*)(p1 + n0), c1 = *(const float4*)(p1 + n1);
            float4 a2 = *(const float4*)(p2 + n0), c2 = *(const float4*)(p2 + n1);
            float4 a3 = *(const float4*)(p3 + n0), c3 = *(const float4*)(p3 + n1);
            {
                unsigned short* q0 = Wblk + (size_t)(kk + 0) * (16 * N);
                unsigned short* q1 = Wblk + (size_t)(kk + 1) * (16 * N);
                unsigned short* q2 = Wblk + (size_t)(kk + 2) * (16 * N);
                unsigned short* q3 = Wblk + (size_t)(kk + 3) * (16 * N);
                *(uint2*)(q0 + n0) = make_uint2(pack2_bf16(a0.x, a0.y), pack2_bf16(a0.z, a0.w));
                *(uint2*)(q0 + n1) = make_uint2(pack2_bf16(c0.x, c0.y), pack2_bf16(c0.z, c0.w));
                *(uint2*)(q1 + n0) = make_uint2(pack2_bf16(a1.x, a1.y), pack2_bf16(a1.z, a1.w));
                *(uint2*)(q1 + n1) = make_uint2(pack2_bf16(c1.x, c1.y), pack2_bf16(c1.z, c1.w));
                *(uint2*)(q2 + n0) = make_uint2(pack2_bf16(a2.x, a2.y), pack2_bf16(a2.z, a2.w));
                *(uint2*)(q2 + n1) = make_uint2(pack2_bf16(c2.x, c2.y), pack2_bf16(c2.z, c2.w));
                *(uint2*)(q3 + n0) = make_uint2(pack2_bf16(a3.x, a3.y), pack2_bf16(a3.z, a3.w));
                *(uint2*)(q3 + n1) = make_uint2(pack2_bf16(c3.x, c3.y), pack2_bf16(c3.z, c3.w));
            }
            float bb0 = b_lds[w + 16 * (kk + 0)];
            float bb1 = b_lds[w + 16 * (kk + 1)];
            float bb2 = b_lds[w + 16 * (kk + 2)];
            float bb3 = b_lds[w + 16 * (kk + 3)];
            float d0 = wave_sum_u(dot8(a0, c0, xa, xb));
            float d1 = wave_sum_u(dot8(a1, c1, xa, xb));
            float d2 = wave_sum_u(dot8(a2, c2, xa, xb));
            float d3 = wave_sum_u(dot8(a3, c3, xa, xb));
            float v0 = fmaxf(d0 - bb0, 0.f);
            float v1 = fmaxf(d1 - bb1, 0.f);
            float v2 = fmaxf(d2 - bb2, 0.f);
            float v3 = fmaxf(d3 - bb3, 0.f);
            sviol += v0 + v1 + v2 + v3;
            ga.x += v0*a0.x + v1*a1.x + v2*a2.x + v3*a3.x;
            ga.y += v0*a0.y + v1*a1.y + v2*a2.y + v3*a3.y;
            ga.z += v0*a0.z + v1*a1.z + v2*a2.z + v3*a3.z;
            ga.w += v0*a0.w + v1*a1.w + v2*a2.w + v3*a3.w;
            gb.x += v0*c0.x + v1*c1.x + v2*c2.x + v3*c3.x;
            gb.y += v0*c0.y + v1*c1.y + v2*c2.y + v3*c3.y;
            gb.z += v0*c0.z + v1*c1.z + v2*c2.z + v3*c3.z;
            gb.w += v0*c0.w + v1*c1.w + v2*c2.w + v3*c3.w;
        }

        if (lane == 0) sv_lds[w] = sviol;
        *(float4*)(&g_lds[w * N + n0]) = ga;
        *(float4*)(&g_lds[w * N + n1]) = gb;
        __syncthreads();
        if (tid == 0) {
            float s = 0.f;
            #pragma unroll
            for (int i = 0; i < NWAVES; ++i) s += sv_lds[i];
            bc_active = (s >= DELTA) ? 1 : 0;
        }
        if (tid < N) {
            float s = 0.f;
            #pragma unroll
            for (int i = 0; i < NWAVES; ++i) s += g_lds[i * N + tid];
            g_lds[tid] = s;
        }
        __syncthreads();
        if (!bc_active) {
            alive = false;
        } else {
            float4 gfa = *(const float4*)(&g_lds[n0]);
            float4 gfb = *(const float4*)(&g_lds[n1]);
            xa.x = fmaxf(xa.x - (ALPHA / (1.f + SCALE*gfa.x)) * gfa.x, 0.f);
            xa.y = fmaxf(xa.y - (ALPHA / (1.f + SCALE*gfa.y)) * gfa.y, 0.f);
            xa.z = fmaxf(xa.z - (ALPHA / (1.f + SCALE*gfa.z)) * gfa.z, 0.f);
            xa.w = fmaxf(xa.w - (ALPHA / (1.f + SCALE*gfa.w)) * gfa.w, 0.f);
            xb.x = fmaxf(xb.x - (ALPHA / (1.f + SCALE*gfb.x)) * gfb.x, 0.f);
            xb.y = fmaxf(xb.y - (ALPHA / (1.f + SCALE*gfb.y)) * gfb.y, 0.f);
            xb.z = fmaxf(xb.z - (ALPHA / (1.f + SCALE*gfb.z)) * gfb.z, 0.f);
            xb.w = fmaxf(xb.w - (ALPHA / (1.f + SCALE*gfb.w)) * gfb.w, 0.f);
        }
    }

    // ---- relayout x into 32-lane-group fragments (via g_lds) ----
    const int h = lane >> 5;          // half-wave index 0/1
    const int s = lane & 31;          // lane-in-half
    __syncthreads();
    if (w == 0) {
        *(float4*)(&g_lds[n0]) = xa;
        *(float4*)(&g_lds[n1]) = xb;
    }
    __syncthreads();
    float4 xf0 = *(const float4*)(&g_lds[  0 + s * 4]);
    float4 xf1 = *(const float4*)(&g_lds[128 + s * 4]);
    float4 xf2 = *(const float4*)(&g_lds[256 + s * 4]);
    float4 xf3 = *(const float4*)(&g_lds[384 + s * 4]);
    __syncthreads();

    // ---- t = 1..50: bf16 phase, half-wave per row, double-buffered ----
    if (alive) {
        // lane's uint2 pointer: block + row (w+16h) + s-th uint2
        const uint2* Wp = (const uint2*)(wsA + (size_t)r * M * N)
                          + (w + 16 * h) * 128 + s;
        const int mb = w + 16 * h;    // b_lds base; row m = mb + 32*G

        uint2 c0, c1, c2, c3, p0, p1, p2, p3;

        #define LOADG(b0, b1, b2, b3, Gn) do {  \
            b0 = Wp[(Gn) * 4096];               \
            b1 = Wp[(Gn) * 4096 + 32];          \
            b2 = Wp[(Gn) * 4096 + 64];          \
            b3 = Wp[(Gn) * 4096 + 96];          \
        } while (0)

        #define COMPUTE(b0, b1, b2, b3, G) do {                               \
            float4 f0, f1, f2, f3;                                            \
            unpack4(b0, f0); unpack4(b1, f1);                                 \
            unpack4(b2, f2); unpack4(b3, f3);                                 \
            float d = f0.x*xf0.x + f0.y*xf0.y + f0.z*xf0.z + f0.w*xf0.w       \
                    + f1.x*xf1.x + f1.y*xf1.y + f1.z*xf1.z + f1.w*xf1.w       \
                    + f2.x*xf2.x + f2.y*xf2.y + f2.z*xf2.z + f2.w*xf2.w       \
                    + f3.x*xf3.x + f3.y*xf3.y + f3.z*xf3.z + f3.w*xf3.w;      \
            d += dpp_mov<0xB1>(d);   /* quad_perm [1,0,3,2] : xor1 */         \
            d += dpp_mov<0x4E>(d);   /* quad_perm [2,3,0,1] : xor2 */         \
            d += dpp_mov<0x141>(d);  /* row_half_mirror     : xor4 */         \
            d += dpp_mov<0x140>(d);  /* row_mirror          : xor8 */         \
            d += __int_as_float(__builtin_amdgcn_ds_swizzle(                  \
                     __float_as_int(d), 0x401F)); /* xor16 within 32 */       \
            float v = fmaxf(d - b_lds[mb + 32 * (G)], 0.f);                   \
            sviol += v;                                                       \
            g0.x += v*f0.x; g0.y += v*f0.y; g0.z += v*f0.z; g0.w += v*f0.w;   \
            g1.x += v*f1.x; g1.y += v*f1.y; g1.z += v*f1.z; g1.w += v*f1.w;   \
            g2.x += v*f2.x; g2.y += v*f2.y; g2.z += v*f2.z; g2.w += v*f2.w;   \
            g3.x += v*f3.x; g3.y += v*f3.y; g3.z += v*f3.z; g3.w += v*f3.w;   \
        } while (0)

        LOADG(c0, c1, c2, c3, 0);   // prologue: G=0 in flight

        for (int t = 1; t < MAXIT; ++t) {
            float4 g0 = make_float4(0.f, 0.f, 0.f, 0.f);
            float4 g1 = make_float4(0.f, 0.f, 0.f, 0.f);
            float4 g2 = make_float4(0.f, 0.f, 0.f, 0.f);
            float4 g3 = make_float4(0.f, 0.f, 0.f, 0.f);
            float sviol = 0.f;

            #pragma unroll 1
            for (int G = 0; G < 16; G += 2) {
                LOADG(p0, p1, p2, p3, G + 1);
                COMPUTE(c0, c1, c2, c3, G);
                LOADG(c0, c1, c2, c3, (G + 2) & 15);  // G=14 -> loads G0 for next iter
                COMPUTE(p0, p1, p2, p3, G + 1);
            }

            // per-half-wave partials -> LDS
            if (s == 0) sv_lds[2 * w + h] = sviol;
            {
                const int gbase = (2 * w + h) * N + s * 4;
                *(float4*)(&g_lds[gbase +   0]) = g0;
                *(float4*)(&g_lds[gbase + 128]) = g1;
                *(float4*)(&g_lds[gbase + 256]) = g2;
                *(float4*)(&g_lds[gbase + 384]) = g3;
            }
            __syncthreads();
            if (tid == 0) {
                float sacc = 0.f;
                #pragma unroll
                for (int i = 0; i < 2 * NWAVES; ++i) sacc += sv_lds[i];
                bc_active = (sacc >= DELTA) ? 1 : 0;
            }
            if (tid < N) {
                float sacc = 0.f;
                #pragma unroll
                for (int i = 0; i < 2 * NWAVES; ++i) sacc += g_lds[i * N + tid];
                g_lds[tid] = sacc;
            }
            __syncthreads();
            if (!bc_active) break;

            float4 q0 = *(const float4*)(&g_lds[  0 + s * 4]);
            float4 q1 = *(const float4*)(&g_lds[128 + s * 4]);
            float4 q2 = *(const float4*)(&g_lds[256 + s * 4]);
            float4 q3 = *(const float4*)(&g_lds[384 + s * 4]);
            xf0.x = fmaxf(xf0.x - (ALPHA / (1.f + SCALE*q0.x)) * q0.x, 0.f);
            xf0.y = fmaxf(xf0.y - (ALPHA / (1.f + SCALE*q0.y)) * q0.y, 0.f);
            xf0.z = fmaxf(xf0.z - (ALPHA / (1.f + SCALE*q0.z)) * q0.z, 0.f);
            xf0.w = fmaxf(xf0.w - (ALPHA / (1.f + SCALE*q0.w)) * q0.w, 0.f);
            xf1.x = fmaxf(xf1.x - (ALPHA / (1.f + SCALE*q1.x)) * q1.x, 0.f);
            xf1.y = fmaxf(xf1.y - (ALPHA / (1.f + SCALE*q1.y)) * q1.y, 0.f);
            xf1.z = fmaxf(xf1.z - (ALPHA / (1.f + SCALE*q1.z)) * q1.z, 0.f);
            xf1.w = fmaxf(xf1.w - (ALPHA / (1.f + SCALE*q1.w)) * q1.w, 0.f);
            xf2.x = fmaxf(xf2.x - (ALPHA / (1.f + SCALE*q2.x)) * q2.x, 0.f);
            xf2.y = fmaxf(xf2.y - (ALPHA / (1.f + SCALE*q2.y)) * q2.y, 0.f);
            xf2.z = fmaxf(xf2.z - (ALPHA / (1.f + SCALE*q2.z)) * q2.z, 0.f);
            xf2.w = fmaxf(xf2.w - (ALPHA / (1.f + SCALE*q2.w)) * q2.w, 0.f);
            xf3.x = fmaxf(xf3.x - (ALPHA / (1.f + SCALE*q3.x)) * q3.x, 0.f);
            xf3.y = fmaxf(xf3.y - (ALPHA / (1.f + SCALE*q3.y)) * q3.y, 0.f);
            xf3.z = fmaxf(xf3.z - (ALPHA / (1.f + SCALE*q3.z)) * q3.z, 0.f);
            xf3.w = fmaxf(xf3.w - (ALPHA / (1.f + SCALE*q3.w)) * q3.w, 0.f);
            __syncthreads();   // protect g_lds before next iter's writes
        }
        #undef LOADG
        #undef COMPUTE
    }

    if (w == 0 && h == 0) {   // x replicated across waves/halves
        float* orow = x_out + (size_t)r * N + s * 4;
        *(float4*)(orow +   0) = xf0;
        *(float4*)(orow + 128) = xf1;
        *(float4*)(orow + 256) = xf2;
        *(float4*)(orow + 384) = xf3;
    }
}

// ---------------------------------------------------------------------------
// Fallback (round-3 proven kernel, fp32) if ws_size < 128 MiB.
// ---------------------------------------------------------------------------
__global__ __launch_bounds__(NTHREADS, 4)
void lva_kernel(const float* __restrict__ x_in,
                const float* __restrict__ A,
                const float* __restrict__ bvec,
                float* __restrict__ x_out)
{
    __shared__ float b_lds[M];
    __shared__ float g_lds[NWAVES * N];
    __shared__ float sv_lds[NWAVES];
    __shared__ int bc_active;

    const int tid  = threadIdx.x;
    const int lane = tid & 63;
    const int w    = tid >> 6;
    const int r    = blockIdx.x;

    if (tid < M) b_lds[tid] = bvec[(size_t)r * M + tid];

    const int n0 = lane * 4;
    const int n1 = 256 + lane * 4;

    const float* xrow = x_in + (size_t)r * N;
    float4 xa = *(const float4*)(xrow + n0);
    float4 xb = *(const float4*)(xrow + n1);

    const float* Ablk = A + (size_t)r * M * N + (size_t)w * N;

    __syncthreads();

    for (int t = 0; t < MAXIT; ++t) {
        float4 ga = make_float4(0.f, 0.f, 0.f, 0.f);
        float4 gb = make_float4(0.f, 0.f, 0.f, 0.f);
        float sviol = 0.f;

        #pragma unroll 1
        for (int kk = 0; kk < MPW; kk += 4) {
            const float* p0 = Ablk + (size_t)(kk + 0) * (16 * N);
            const float* p1 = Ablk + (size_t)(kk + 1) * (16 * N);
            const float* p2 = Ablk + (size_t)(kk + 2) * (16 * N);
            const float* p3 = Ablk + (size_t)(kk + 3) * (16 * N);
            float4 a0 = *(const float4*)(p0 + n0), c0 = *(const float4*)(p0 + n1);
            float4 a1 = *(const float4*)(p1 + n0), c1 = *(const float4*)(p1 + n1);
            float4 a2 = *(const float4*)(p2 + n0), c2 = *(const float4*)(p2 + n1);
            float4 a3 = *(const float4*)(p3 + n0), c3 = *(const float4*)(p3 + n1);
            float bb0 = b_lds[w + 16 * (kk + 0)];
            float bb1 = b_lds[w + 16 * (kk + 1)];
            float bb2 = b_lds[w + 16 * (kk + 2)];
            float bb3 = b_lds[w + 16 * (kk + 3)];
            float d0 = wave_sum_u(dot8(a0, c0, xa, xb));
            float d1 = wave_sum_u(dot8(a1, c1, xa, xb));
            float d2 = wave_sum_u(dot8(a2, c2, xa, xb));
            float d3 = wave_sum_u(dot8(a3, c3, xa, xb));
            float v0 = fmaxf(d0 - bb0, 0.f);
            float v1 = fmaxf(d1 - bb1, 0.f);
            float v2 = fmaxf(d2 - bb2, 0.f);
            float v3 = fmaxf(d3 - bb3, 0.f);
            sviol += v0 + v1 + v2 + v3;
            ga.x += v0*a0.x + v1*a1.x + v2*a2.x + v3*a3.x;
            ga.y += v0*a0.y + v1*a1.y + v2*a2.y + v3*a3.y;
            ga.z += v0*a0.z + v1*a1.z + v2*a2.z + v3*a3.z;
            ga.w += v0*a0.w + v1*a1.w + v2*a2.w + v3*a3.w;
            gb.x += v0*c0.x + v1*c1.x + v2*c2.x + v3*c3.x;
            gb.y += v0*c0.y + v1*c1.y + v2*c2.y + v3*c3.y;
            gb.z += v0*c0.z + v1*c1.z + v2*c2.z + v3*c3.z;
            gb.w += v0*c0.w + v1*c1.w + v2*c2.w + v3*c3.w;
        }

        if (lane == 0) sv_lds[w] = sviol;
        *(float4*)(&g_lds[w * N + n0]) = ga;
        *(float4*)(&g_lds[w * N + n1]) = gb;
        __syncthreads();
        if (tid == 0) {
            float sacc = 0.f;
            #pragma unroll
            for (int i = 0; i < NWAVES; ++i) sacc += sv_lds[i];
            bc_active = (sacc >= DELTA) ? 1 : 0;
        }
        if (tid < N) {
            float sacc = 0.f;
            #pragma unroll
            for (int i = 0; i < NWAVES; ++i) sacc += g_lds[i * N + tid];
            g_lds[tid] = sacc;
        }
        __syncthreads();
        if (!bc_active) break;

        float4 gfa = *(const float4*)(&g_lds[n0]);
        float4 gfb = *(const float4*)(&g_lds[n1]);
        xa.x = fmaxf(xa.x - (ALPHA / (1.f + SCALE*gfa.x)) * gfa.x, 0.f);
        xa.y = fmaxf(xa.y - (ALPHA / (1.f + SCALE*gfa.y)) * gfa.y, 0.f);
        xa.z = fmaxf(xa.z - (ALPHA / (1.f + SCALE*gfa.z)) * gfa.z, 0.f);
        xa.w = fmaxf(xa.w - (ALPHA / (1.f + SCALE*gfa.w)) * gfa.w, 0.f);
        xb.x = fmaxf(xb.x - (ALPHA / (1.f + SCALE*gfb.x)) * gfb.x, 0.f);
        xb.y = fmaxf(xb.y - (ALPHA / (1.f + SCALE*gfb.y)) * gfb.y, 0.f);
        xb.z = fmaxf(xb.z - (ALPHA / (1.f + SCALE*gfb.z)) * gfb.z, 0.f);
        xb.w = fmaxf(xb.w - (ALPHA / (1.f + SCALE*gfb.w)) * gfb.w, 0.f);
        __syncthreads();
    }

    float* orow = x_out + (size_t)r * N;
    if (w == 0) {
        *(float4*)(orow + n0) = xa;
        *(float4*)(orow + n1) = xb;
    }
}

extern "C" void kernel_launch(void* const* d_in, const int* in_sizes, int n_in,
                              void* d_out, int out_size, void* d_ws, size_t ws_size,
                              hipStream_t stream)
{
    const float* x  = (const float*)d_in[0];
    const float* A  = (const float*)d_in[1];
    const float* b  = (const float*)d_in[2];
    float* out      = (float*)d_out;

    if (ws_size >= WS_NEEDED) {
        lva_bf16_kernel<<<dim3(NROWS), dim3(NTHREADS), 0, stream>>>(
            x, A, b, out, (unsigned short*)d_ws);
    } else {
        lva_kernel<<<dim3(NROWS), dim3(NTHREADS), 0, stream>>>(x, A, b, out);
    }
}